// Round 12
// baseline (83.775 us; speedup 1.0000x reference)
//
#include <hip/hip_runtime.h>

#define NCLS 19
#define HWPIX (512 * 512)
#define NB 8
#define PB 64
#define ALPHA_C 0.7f
#define BETA_C 0.3f
#define EPS_C 1e-7f
#define L2E 1.44269504088896f

typedef float v2f __attribute__((ext_vector_type(2)));

// R12: two-pass-over-L2 softmax -- the duty-cycle fix that fits in registers.
// One-pass softmax must hold e[0..18] until the denominator exists (76 VGPRs
// -> burst-then-stall, or spills when pipelined: R11). Split instead:
//   pass A: stream 19 classes, running sum only (8 acc regs, no per-class
//           state) -> loads have no storage constraint, compiler pipelines
//           them like a plain reduction stream.
//   pass B: re-read the same 77 KB chunk (L2-resident: ~2.5 MB/XCD working
//           set < 4 MB) and accumulate S/TP with register selects.
// HBM traffic unchanged (pass B is L2-hot); exp runs twice (~6 us VALU
// total, irrelevant). Disguised pointer (asm "+s") stops the compiler from
// CSE-ing pass-B reloads into pass-A storage. N via proven 32-copy bins;
// S/TP in registers + butterfly; R5 ticket tail.
__global__ __launch_bounds__(256, 3) void ftl_fused(
    const float* __restrict__ x,    // [B, C, H, W]
    const int* __restrict__ tgt,    // [B, H, W]
    float* __restrict__ part,       // [B*PB][3*NCLS]  (S | TP | N)
    int* __restrict__ counter,      // zeroed by hipMemsetAsync pre-launch
    float* __restrict__ out) {
  const int b = blockIdx.x / PB;
  const int blk = blockIdx.x % PB;
  const int tid = threadIdx.x;

  __shared__ float sS[NCLS], sTP[NCLS];
  __shared__ int sNb[NCLS][32];
  for (int i = tid; i < NCLS * 32; i += 256) (&sNb[0][0])[i] = 0;
  if (tid < NCLS) { sS[tid] = 0.f; sTP[tid] = 0.f; }
  __syncthreads();

  const float* xb = x + (size_t)b * NCLS * HWPIX;
  const int* tb = tgt + (size_t)b * HWPIX;
  const int cp = tid & 31;

  // Same-value pointer the compiler cannot prove equal to xb: pass-B loads
  // through it cannot be CSE'd against pass-A loads (which would silently
  // rebuild the 76-register one-pass kernel).
  const float* xb2 = xb;
  asm("" : "+s"(xb2));

  v2f S2[NCLS], TP2[NCLS];
#pragma unroll
  for (int c = 0; c < NCLS; ++c) {
    S2[c] = (v2f){0.f, 0.f};
    TP2[c] = (v2f){0.f, 0.f};
  }

  const int base = blk * 4096;  // 64 blocks/image * 4096 pixels
  for (int it = 0; it < 4; ++it) {
    const int pix = base + it * 1024 + tid * 4;
    const int4 t = *reinterpret_cast<const int4*>(tb + pix);

    // ---- pass A: sum of exps; no per-class storage -> deep load pipeline ----
    v2f sa = (v2f){0.f, 0.f}, sb = (v2f){0.f, 0.f};
#pragma unroll
    for (int c = 0; c < NCLS; ++c) {
      const float4 xv =
          *reinterpret_cast<const float4*>(xb + (size_t)c * HWPIX + pix);
      sa += (v2f){__builtin_amdgcn_exp2f(xv.x * L2E),
                  __builtin_amdgcn_exp2f(xv.y * L2E)};
      sb += (v2f){__builtin_amdgcn_exp2f(xv.z * L2E),
                  __builtin_amdgcn_exp2f(xv.w * L2E)};
    }
    const v2f inva = (v2f){__builtin_amdgcn_rcpf(sa.x),
                           __builtin_amdgcn_rcpf(sa.y)};
    const v2f invb = (v2f){__builtin_amdgcn_rcpf(sb.x),
                           __builtin_amdgcn_rcpf(sb.y)};

    // ---- pass B: re-stream the chunk (L2-hot), accumulate S and TP ----
#pragma unroll
    for (int c = 0; c < NCLS; ++c) {
      const float4 xv =
          *reinterpret_cast<const float4*>(xb2 + (size_t)c * HWPIX + pix);
      const v2f pa = (v2f){__builtin_amdgcn_exp2f(xv.x * L2E),
                           __builtin_amdgcn_exp2f(xv.y * L2E)} * inva;
      const v2f pb = (v2f){__builtin_amdgcn_exp2f(xv.z * L2E),
                           __builtin_amdgcn_exp2f(xv.w * L2E)} * invb;
      S2[c] += pa + pb;
      TP2[c] += (v2f){(t.x == c ? pa.x : 0.f) + (t.z == c ? pb.x : 0.f),
                      (t.y == c ? pa.y : 0.f) + (t.w == c ? pb.y : 0.f)};
    }
    atomicAdd(&sNb[t.x][cp], 1);
    atomicAdd(&sNb[t.y][cp], 1);
    atomicAdd(&sNb[t.z][cp], 1);
    atomicAdd(&sNb[t.w][cp], 1);
  }

  // ---- block epilogue: butterfly the 38 register accumulators ----
#pragma unroll
  for (int c = 0; c < NCLS; ++c) {
    float Sc = S2[c].x + S2[c].y;
    float Tc = TP2[c].x + TP2[c].y;
    for (int off = 32; off; off >>= 1) {
      Sc += __shfl_down(Sc, off);
      Tc += __shfl_down(Tc, off);
    }
    if ((tid & 63) == 0) {
      atomicAdd(&sS[c], Sc);
      atomicAdd(&sTP[c], Tc);
    }
  }
  __syncthreads();
  if (tid < NCLS) {
    int n = 0;
#pragma unroll
    for (int i = 0; i < 32; ++i) n += sNb[tid][i];
    float* p = part + (size_t)blockIdx.x * (3 * NCLS);
    p[tid] = sS[tid];
    p[NCLS + tid] = sTP[tid];
    p[2 * NCLS + tid] = (float)n;
  }

  // ---- last-block final reduction (R5 ticket tail) ----
  __syncthreads();  // part-slice stores drained (waitcnt before barrier)
  __shared__ int lastFlag;
  if (tid == 0) {
    __threadfence();  // release: make this block's slice device-visible
    lastFlag = (atomicAdd(counter, 1) == (NB * PB - 1));
  }
  __syncthreads();
  if (!lastFlag) return;
  __threadfence();  // acquire: invalidate stale cached partials

  float v = 0.f;
  if (tid < NB * NCLS) {
    const int bb = tid / NCLS;
    const int c = tid % NCLS;
    float S = 0.f, TP = 0.f, Nc = 0.f;
#pragma unroll 16
    for (int p = 0; p < PB; ++p) {
      const float* q = part + (size_t)(bb * PB + p) * (3 * NCLS);
      S += q[c];
      TP += q[NCLS + c];
      Nc += q[2 * NCLS + c];
    }
    const float FPv = S - TP;
    const float FNv = Nc - TP;
    const float tv = (TP + EPS_C) / (TP + ALPHA_C * FNv + BETA_C * FPv + EPS_C);
    v = 1.0f - tv;  // GAMMA == 1.0
  }
  for (int off = 32; off; off >>= 1) v += __shfl_down(v, off);
  __shared__ float wsum[4];
  if ((tid & 63) == 0) wsum[tid >> 6] = v;
  __syncthreads();
  if (tid == 0) out[0] = (wsum[0] + wsum[1] + wsum[2] + wsum[3]) / (float)NB;
}

extern "C" void kernel_launch(void* const* d_in, const int* in_sizes, int n_in,
                              void* d_out, int out_size, void* d_ws, size_t ws_size,
                              hipStream_t stream) {
  const float* x = (const float*)d_in[0];
  const int* tgt = (const int*)d_in[1];
  float* out = (float*)d_out;
  float* part = (float*)d_ws;
  int* counter = (int*)(part + NB * PB * 3 * NCLS);  // right after partials

  hipMemsetAsync(counter, 0, sizeof(int), stream);  // graph-capturable
  ftl_fused<<<NB * PB, 256, 0, stream>>>(x, tgt, part, counter, out);
}

// Round 13
// 50.986 us; speedup vs baseline: 1.6431x; 1.6431x over previous
//
#include <hip/hip_runtime.h>

#define NCLS 19
#define HWPIX (512 * 512)
#define NB 8
#define PB 64
#define NCH 8                  // chunks per block
#define CPX 512                // pixels per chunk (256 thr x 2)
#define ALPHA_C 0.7f
#define BETA_C 0.3f
#define EPS_C 1e-7f
#define L2E 1.44269504088896f

typedef float v2f __attribute__((ext_vector_type(2)));

// R13: LDS-as-thread-private-spill two-pass. The one-pass kernel (R5) must
// keep 19 e-values live in VGPRs until the denominator exists -> the load
// engine idles during each ~1000cy compute phase (duty-cycle cap). R11
// (register prefetch) spilled; R12 (re-read via L2) thrashed (7 MB/XCD > 4
// MB). Fix: each thread spills its 19 e-values to a PRIVATE 152 B LDS slot.
//   pass A per class: float2 load -> exp -> sum += e -> ds_write stage[c][tid]
//     (~2 live VGPRs per class -> compiler hoists many independent stream
//      loads ahead; sustained in-flight bytes instead of burst-then-stall)
//   pass B per class: ds_read own slot -> p = e*inv -> S/TP accumulate.
// Same-thread LDS -> NO barriers in the loop, no cross-thread traffic.
// stage[c][tid] b64 layout is bank-conflict-free. LDS ~39 KB; accumulators
// in regs (R12 proved they fit); N via 32-copy bins; R5 ticket tail.
__global__ __launch_bounds__(256, 2) void ftl_fused(
    const float* __restrict__ x,    // [B, C, H, W]
    const int* __restrict__ tgt,    // [B, H, W]
    float* __restrict__ part,       // [B*PB][3*NCLS]  (S | TP | N)
    int* __restrict__ counter,      // zeroed by hipMemsetAsync pre-launch
    float* __restrict__ out) {
  const int b = blockIdx.x / PB;
  const int blk = blockIdx.x % PB;
  const int tid = threadIdx.x;

  __shared__ v2f stage[NCLS][256];   // 38912 B thread-private spill slots
  __shared__ float sS[NCLS], sTP[NCLS];
  __shared__ int sNb[NCLS][32];
  for (int i = tid; i < NCLS * 32; i += 256) (&sNb[0][0])[i] = 0;
  if (tid < NCLS) { sS[tid] = 0.f; sTP[tid] = 0.f; }
  __syncthreads();

  const float* xb = x + (size_t)b * NCLS * HWPIX;
  const int* tb = tgt + (size_t)b * HWPIX;
  const int cp = tid & 31;

  v2f S2[NCLS], TP2[NCLS];
#pragma unroll
  for (int c = 0; c < NCLS; ++c) {
    S2[c] = (v2f){0.f, 0.f};
    TP2[c] = (v2f){0.f, 0.f};
  }

  const int base = blk * (NCH * CPX);  // 4096 pixels per block
  for (int ch = 0; ch < NCH; ++ch) {
    const int pix = base + ch * CPX + tid * 2;
    const int2 t = *reinterpret_cast<const int2*>(tb + pix);

    // ---- pass A: stream 19 classes; e spilled to private LDS slot ----
    v2f sum = (v2f){0.f, 0.f};
#pragma unroll
    for (int c = 0; c < NCLS; ++c) {
      const float2 xv =
          *reinterpret_cast<const float2*>(xb + (size_t)c * HWPIX + pix);
      const v2f e = (v2f){__builtin_amdgcn_exp2f(xv.x * L2E),
                          __builtin_amdgcn_exp2f(xv.y * L2E)};
      sum += e;
      stage[c][tid] = e;         // ds_write_b64, conflict-free, own slot
    }
    const v2f inv = (v2f){__builtin_amdgcn_rcpf(sum.x),
                          __builtin_amdgcn_rcpf(sum.y)};

    // ---- pass B: read own slots back, accumulate S / TP ----
#pragma unroll
    for (int c = 0; c < NCLS; ++c) {
      const v2f e = stage[c][tid];  // ds_read_b64, own slot (no barrier)
      const v2f p = e * inv;
      S2[c] += p;
      TP2[c] += (v2f){(t.x == c) ? p.x : 0.f, (t.y == c) ? p.y : 0.f};
    }
    atomicAdd(&sNb[t.x][cp], 1);
    atomicAdd(&sNb[t.y][cp], 1);
  }

  // ---- block epilogue: butterfly the 38 register accumulators ----
#pragma unroll
  for (int c = 0; c < NCLS; ++c) {
    float Sc = S2[c].x + S2[c].y;
    float Tc = TP2[c].x + TP2[c].y;
    for (int off = 32; off; off >>= 1) {
      Sc += __shfl_down(Sc, off);
      Tc += __shfl_down(Tc, off);
    }
    if ((tid & 63) == 0) {
      atomicAdd(&sS[c], Sc);
      atomicAdd(&sTP[c], Tc);
    }
  }
  __syncthreads();
  if (tid < NCLS) {
    int n = 0;
#pragma unroll
    for (int i = 0; i < 32; ++i) n += sNb[tid][i];
    float* p = part + (size_t)blockIdx.x * (3 * NCLS);
    p[tid] = sS[tid];
    p[NCLS + tid] = sTP[tid];
    p[2 * NCLS + tid] = (float)n;
  }

  // ---- last-block final reduction (R5 ticket tail) ----
  __syncthreads();  // part-slice stores drained (waitcnt before barrier)
  __shared__ int lastFlag;
  if (tid == 0) {
    __threadfence();  // release: make this block's slice device-visible
    lastFlag = (atomicAdd(counter, 1) == (NB * PB - 1));
  }
  __syncthreads();
  if (!lastFlag) return;
  __threadfence();  // acquire: invalidate stale cached partials

  float v = 0.f;
  if (tid < NB * NCLS) {
    const int bb = tid / NCLS;
    const int c = tid % NCLS;
    float S = 0.f, TP = 0.f, Nc = 0.f;
#pragma unroll 16
    for (int p = 0; p < PB; ++p) {
      const float* q = part + (size_t)(bb * PB + p) * (3 * NCLS);
      S += q[c];
      TP += q[NCLS + c];
      Nc += q[2 * NCLS + c];
    }
    const float FPv = S - TP;
    const float FNv = Nc - TP;
    const float tv = (TP + EPS_C) / (TP + ALPHA_C * FNv + BETA_C * FPv + EPS_C);
    v = 1.0f - tv;  // GAMMA == 1.0
  }
  for (int off = 32; off; off >>= 1) v += __shfl_down(v, off);
  __shared__ float wsum[4];
  if ((tid & 63) == 0) wsum[tid >> 6] = v;
  __syncthreads();
  if (tid == 0) out[0] = (wsum[0] + wsum[1] + wsum[2] + wsum[3]) / (float)NB;
}

extern "C" void kernel_launch(void* const* d_in, const int* in_sizes, int n_in,
                              void* d_out, int out_size, void* d_ws, size_t ws_size,
                              hipStream_t stream) {
  const float* x = (const float*)d_in[0];
  const int* tgt = (const int*)d_in[1];
  float* out = (float*)d_out;
  float* part = (float*)d_ws;
  int* counter = (int*)(part + NB * PB * 3 * NCLS);  // right after partials

  hipMemsetAsync(counter, 0, sizeof(int), stream);  // graph-capturable
  ftl_fused<<<NB * PB, 256, 0, stream>>>(x, tgt, part, counter, out);
}